// Round 10
// baseline (703.599 us; speedup 1.0000x reference)
//
#include <hip/hip_runtime.h>

typedef unsigned long long u64;
typedef unsigned int u32;
typedef unsigned short u16;

// Problem constants (from reference setup_inputs / NUM_GROUP / GROUP_SIZE)
#define BATCH 32
#define NPTS  8192
#define NGRP  512
#define KNN_K 32

#define FPS_T 1024                 // threads per FPS block (16 waves)
#define FPS_W (FPS_T / 64)         // 16 waves = 16 z-slabs
#define PPT   (NPTS / FPS_T)       // 8 points per thread (scalar regs)
#define KNN_WPB 4                  // waves (centers) per kNN block
#define QCAP 128                   // per-wave LDS candidate buffer depth

// Exact IEEE (no FMA contraction) squared distance: ((dx*dx + dy*dy) + dz*dz)
__device__ __forceinline__ float sq3(float dx, float dy, float dz) {
    return __fadd_rn(__fadd_rn(__fmul_rn(dx, dx), __fmul_rn(dy, dy)), __fmul_rn(dz, dz));
}

// d >= 0 always (sum of squares) -> IEEE bits are order-monotonic.
// key = (d_bits << 32) | idx  ==> u64 ascending == (d, idx) lexicographic.
__device__ __forceinline__ u64 packdi(float d, int n) {
    return ((u64)__float_as_uint(d) << 32) | (u32)n;
}

__device__ __forceinline__ u64 umin64(u64 a, u64 b) { return a < b ? a : b; }
__device__ __forceinline__ u64 umax64(u64 a, u64 b) { return a > b ? a : b; }

__device__ __forceinline__ u64 shfl_xor_u64(u64 v, int m) {
    int lo = __shfl_xor((int)(u32)v, m, 64);
    int hi = __shfl_xor((int)(u32)(v >> 32), m, 64);
    return ((u64)(u32)hi << 32) | (u32)lo;
}

__device__ __forceinline__ u64 shfl_u64(u64 v, int src) {
    int lo = __shfl((int)(u32)v, src, 64);
    int hi = __shfl((int)(u32)(v >> 32), src, 64);
    return ((u64)(u32)hi << 32) | (u32)lo;
}

// ---- DPP wave-64 u64-max reduction (result valid in lane 63) --------------
// update_dpp(old=0, bound_ctrl=1): lanes with invalid DPP source read 0.
// 0 is a safe identity: every real fps key has bits16..31 = (0xFFFF^oidx)
// >= 0xE000 (oidx < 8192), so real keys are always > 0.
template <int CTRL>
__device__ __forceinline__ u64 dpp_max_step(u64 k) {
    u32 plo = (u32)__builtin_amdgcn_update_dpp(0, (int)(u32)k, CTRL, 0xF, 0xF, true);
    u32 phi = (u32)__builtin_amdgcn_update_dpp(0, (int)(u32)(k >> 32), CTRL, 0xF, 0xF, true);
    u64 p = ((u64)phi << 32) | plo;
    return k > p ? k : p;
}
__device__ __forceinline__ u64 dpp_wave_max(u64 k) {
    k = dpp_max_step<0x111>(k);  // row_shr:1
    k = dpp_max_step<0x112>(k);  // row_shr:2
    k = dpp_max_step<0x114>(k);  // row_shr:4
    k = dpp_max_step<0x118>(k);  // row_shr:8   -> lanes 15/31/47/63 = row max
    k = dpp_max_step<0x142>(k);  // row_bcast15 -> lane31 = rows0-1, lane63 = rows2-3
    k = dpp_max_step<0x143>(k);  // row_bcast31 -> lane63 = full wave
    return k;
}

// Cross-lane bitonic sort: one u64 per lane -> ascending by lane index.
__device__ __forceinline__ u64 lane_sort64(u64 v, int lane) {
#pragma unroll
    for (int k = 2; k <= 64; k <<= 1) {
#pragma unroll
        for (int j = k >> 1; j > 0; j >>= 1) {
            u64 p = shfl_xor_u64(v, j);
            bool keepmin = (((lane & k) == 0) == ((lane & j) == 0));
            u64 mn = umin64(v, p), mx = umax64(v, p);
            v = keepmin ? mn : mx;
        }
    }
    return v;
}

// m, c both ascending-sorted across lanes; returns the lowest 64 of the 128,
// ascending-sorted. (reverse c, elementwise min -> bitonic, 6-level clean)
__device__ __forceinline__ u64 lane_merge64(u64 m, u64 c, int lane) {
    u64 cr = shfl_xor_u64(c, 63);
    u64 z = umin64(m, cr);
#pragma unroll
    for (int dd = 32; dd > 0; dd >>= 1) {
        u64 p = shfl_xor_u64(z, dd);
        u64 mn = umin64(z, p), mx = umax64(z, p);
        z = (lane & dd) ? mx : mn;
    }
    return z;
}

__device__ __forceinline__ float bf_min(float v) {
#pragma unroll
    for (int off = 1; off < 64; off <<= 1) v = fminf(v, __shfl_xor(v, off, 64));
    return v;
}
__device__ __forceinline__ float bf_max(float v) {
#pragma unroll
    for (int off = 1; off < 64; off <<= 1) v = fmaxf(v, __shfl_xor(v, off, 64));
    return v;
}

// ---------------------------------------------------------------------------
// Slab-pruned FPS: one block per batch, 1024 threads = 16 waves = 16 approx
// z-slabs (Phi-approx binning + LDS scatter, one-time). Wave w owns sorted
// positions [512w, 512(w+1)) in registers (R8 scalar core) + its exact AABB.
// Per round: wave-uniform skip iff lb(AABB,c)*(1-1e-5) >= wave_maxmd --
// provably no md in the wave can change (d_ref >= true_d >= lb_true >=
// lb_fp*(1-9eps) > maxmd >= md[p]), so the wave's stored argmax key is
// still exact and is simply republished. Active waves: dist+min, max-tree,
// descending slot scan (exact-tie fallback via sidx on the rare md-equality
// path), key = (md32 | ~oidx16 | pos16) -> DPP wave argmax -> LDS.
// One barrier per round; all threads reduce the 16 keys; coords fetched by
// pos (b32 broadcasts). Centers buffered in LDS, written once at the end.
// ---------------------------------------------------------------------------
__global__ __launch_bounds__(FPS_T) void fps_kernel(const float* __restrict__ in,
                                                    float* __restrict__ centers) {
    __shared__ float sx[NPTS];           // 32 KB (slab-sorted)
    __shared__ float sy[NPTS];           // 32 KB
    __shared__ float sz[NPTS];           // 32 KB
    __shared__ u16   sidx[NPTS];         // 16 KB (sorted pos -> orig idx)
    __shared__ u64   s_key[2][FPS_W];    // double-buffered wave keys
    __shared__ float s_out[NGRP * 3];    // 6 KB center-coord buffer
    __shared__ float s_red[2 * FPS_W];   // stats partials
    __shared__ float s_stats[2];         // mu, inv_sigma (z axis)
    __shared__ int   s_hist[FPS_W];
    __shared__ int   s_off[FPS_W];

    const int b = blockIdx.x;
    const int t = threadIdx.x;
    const int w = t >> 6;
    const int lane = t & 63;
    const float* xp = in + (size_t)b * 3 * NPTS;
    const float* yp = xp + NPTS;
    const float* zp = xp + 2 * NPTS;

    // ---- binning: z stats ----
    float ztmp[PPT];
    float zsum = 0.f, zsq = 0.f;
#pragma unroll
    for (int i = 0; i < PPT; ++i) {
        int n = i * FPS_T + t;
        float z = zp[n];
        ztmp[i] = z;
        zsum += z;
        zsq += z * z;
    }
#pragma unroll
    for (int off = 1; off < 64; off <<= 1) {
        zsum += __shfl_xor(zsum, off, 64);
        zsq  += __shfl_xor(zsq,  off, 64);
    }
    if (lane == 0) { s_red[w] = zsum; s_red[FPS_W + w] = zsq; }
    if (t < FPS_W) s_hist[t] = 0;
    __syncthreads();
    if (t == 0) {
        float S = 0.f, Q = 0.f;
        for (int i = 0; i < FPS_W; ++i) { S += s_red[i]; Q += s_red[FPS_W + i]; }
        float mu = S / (float)NPTS;
        float var = Q / (float)NPTS - mu * mu;
        s_stats[0] = mu;
        s_stats[1] = rsqrtf(fmaxf(var, 1e-12f));
    }
    __syncthreads();
    const float mu = s_stats[0], invs = s_stats[1];

    // ---- slab id per point (Phi ~ logistic; balance-only, any map is correct)
    int slab[PPT];
#pragma unroll
    for (int i = 0; i < PPT; ++i) {
        float u = (ztmp[i] - mu) * invs * 1.702f;
        float sg = 1.0f / (1.0f + __expf(-u));
        int sb = (int)(sg * (float)FPS_W);
        slab[i] = min(FPS_W - 1, max(0, sb));
        atomicAdd(&s_hist[slab[i]], 1);
    }
    __syncthreads();
    if (t < FPS_W) {
        int acc = 0;
        for (int j = 0; j < t; ++j) acc += s_hist[j];
        s_off[t] = acc;
    }
    __syncthreads();
    // ---- scatter (order within slab irrelevant; ties handled via oidx) ----
#pragma unroll
    for (int i = 0; i < PPT; ++i) {
        int n = i * FPS_T + t;
        int pos = atomicAdd(&s_off[slab[i]], 1);
        sx[pos] = xp[n];
        sy[pos] = yp[n];
        sz[pos] = ztmp[i];
        sidx[pos] = (u16)n;
    }
    __syncthreads();

    // ---- reload into registers: wave w owns positions [512w, 512(w+1)) ----
    float xr[PPT], yr[PPT], zr[PPT], md[PPT];
#pragma unroll
    for (int i = 0; i < PPT; ++i) {
        int p = (w << 9) + (i << 6) + lane;
        xr[i] = sx[p]; yr[i] = sy[p]; zr[i] = sz[p];
        md[i] = 1e10f;
    }
    // ---- exact wave AABB ----
    float lx = xr[0], hx = xr[0], ly = yr[0], hy = yr[0], lz = zr[0], hz = zr[0];
#pragma unroll
    for (int i = 1; i < PPT; ++i) {
        lx = fminf(lx, xr[i]); hx = fmaxf(hx, xr[i]);
        ly = fminf(ly, yr[i]); hy = fmaxf(hy, yr[i]);
        lz = fminf(lz, zr[i]); hz = fmaxf(hz, zr[i]);
    }
    lx = bf_min(lx); hx = bf_max(hx);
    ly = bf_min(ly); hy = bf_max(hy);
    lz = bf_min(lz); hz = bf_max(hz);

    float cx = xp[0], cy = yp[0], cz = zp[0];  // farthest starts at orig idx 0
    float prev_maxmd = 1e10f;                  // forces round-0 active
    u64 prevkey = 0;

    for (int r = 0; r < NGRP; ++r) {
        if (t == 0) {  // idxs[r] is the PRE-update farthest -> buffer coords
            s_out[r * 3 + 0] = cx;
            s_out[r * 3 + 1] = cy;
            s_out[r * 3 + 2] = cz;
        }
        // wave-uniform prune test (margin 1e-5 >> accumulated fp32 error)
        float gx = fmaxf(0.f, fmaxf(lx - cx, cx - hx));
        float gy = fmaxf(0.f, fmaxf(ly - cy, cy - hy));
        float gz = fmaxf(0.f, fmaxf(lz - cz, cz - hz));
        float lb = gx * gx + gy * gy + gz * gz;
        if (lb * 0.99999f < prev_maxmd) {  // ACTIVE
#pragma unroll
            for (int i = 0; i < PPT; ++i) {
                float d = sq3(__fsub_rn(xr[i], cx), __fsub_rn(yr[i], cy),
                              __fsub_rn(zr[i], cz));
                md[i] = fminf(md[i], d);
            }
            // max-tree over 8 (v_max returns operand bits exactly)
            float m01 = fmaxf(md[0], md[1]), m23 = fmaxf(md[2], md[3]);
            float m45 = fmaxf(md[4], md[5]), m67 = fmaxf(md[6], md[7]);
            float mxs = fmaxf(fmaxf(m01, m23), fmaxf(m45, m67));
            // descending slot scan + match count
            int s = 0, cnt = 0;
#pragma unroll
            for (int i = PPT - 1; i >= 0; --i) {
                bool h = (md[i] == mxs);
                if (h) s = i;
                cnt += (int)h;
            }
            int p = (w << 9) + (s << 6) + lane;
            u32 oidx;
            if (cnt > 1) {  // rare exact-tie path: min orig idx among matches
                oidx = 0xFFFFu;
#pragma unroll
                for (int i = 0; i < PPT; ++i) {
                    if (md[i] == mxs) {
                        int pp = (w << 9) + (i << 6) + lane;
                        u32 oi = (u32)sidx[pp];
                        if (oi < oidx) { oidx = oi; p = pp; }
                    }
                }
            } else {
                oidx = (u32)sidx[p];
            }
            // key: (md, smaller oidx wins) with pos riding in low 16 bits
            u64 k = ((u64)__float_as_uint(mxs) << 32) |
                    ((u64)(0xFFFFu ^ oidx) << 16) | (u32)p;
            k = dpp_wave_max(k);
            if (lane == 63) s_key[r & 1][w] = k;
        } else {  // SKIPPED: md unchanged -> stored key still exact
            if (lane == 63) s_key[r & 1][w] = prevkey;
        }
        __syncthreads();
        u64 m = s_key[r & 1][0];
#pragma unroll
        for (int i = 1; i < FPS_W; ++i) m = umax64(m, s_key[r & 1][i]);
        prevkey = s_key[r & 1][w];
        prev_maxmd = __uint_as_float((u32)(prevkey >> 32));
        int cp = (int)(m & 0xFFFFu);
        cx = sx[cp]; cy = sy[cp]; cz = sz[cp];  // b32 broadcast reads
    }

    __syncthreads();  // t0's last s_out writes
    float* cdst = centers + (size_t)b * NGRP * 3;
    for (int i = t; i < NGRP * 3; i += FPS_T) cdst[i] = s_out[i];
}

// ---------------------------------------------------------------------------
// kNN + gather: one wave per center. Wave-cooperative exact top-32 with a
// DEFERRED LDS candidate buffer: m = sorted-64 register list (lanes 0..31 =
// exact running top-32 of all merged keys), tau = m[31] (exact 32nd).
// Candidates (kk < tau) are compacted into a 128-deep per-wave LDS buffer
// via ballot+mbcnt (no atomics); sort64+merge fires only when >=64 have
// accumulated. Strict < filter + unique keys => exactness; drain loop
// merges leftovers. (R6-R9: ~165 us, unchanged.)
// ---------------------------------------------------------------------------
__global__ __launch_bounds__(KNN_WPB * 64) void knn_kernel(const float* __restrict__ in,
                                                           const float* __restrict__ centers,
                                                           float* __restrict__ out) {
    __shared__ u64 sbuf[KNN_WPB][QCAP];  // 4 KB candidate buffers

    const int wave = threadIdx.x >> 6;
    const int lane = threadIdx.x & 63;
    const int cid  = blockIdx.x * KNN_WPB + wave;   // [0, B*G)
    const int b    = cid >> 9;                      // /NGRP

    const float* xp = in + (size_t)b * 3 * NPTS;
    const float* yp = xp + NPTS;
    const float* zp = xp + 2 * NPTS;

    const float cx = centers[cid * 3 + 0];
    const float cy = centers[cid * 3 + 1];
    const float cz = centers[cid * 3 + 2];

    // seed: column 0 (points 0..63), exact sorted top-64
    float x = xp[lane], y = yp[lane], z = zp[lane];
    u64 m = packdi(sq3(__fsub_rn(x, cx), __fsub_rn(y, cy), __fsub_rn(z, cz)), lane);
    m = lane_sort64(m, lane);
    u64 tau = shfl_u64(m, 31);
    int cnt = 0;  // wave-uniform buffered-candidate count

    float nx = xp[64 + lane], ny = yp[64 + lane], nz = zp[64 + lane];
#pragma unroll 1
    for (int j = 1; j < NPTS / 64; ++j) {
        x = nx; y = ny; z = nz;
        if (j + 1 < NPTS / 64) {  // 1-deep prefetch
            int n2 = (j + 1) * 64 + lane;
            nx = xp[n2]; ny = yp[n2]; nz = zp[n2];
        }
        float d = sq3(__fsub_rn(x, cx), __fsub_rn(y, cy), __fsub_rn(z, cz));
        u64 kk = packdi(d, j * 64 + lane);
        bool cand = kk < tau;  // strict: excluded keys provably > global 32nd
        u64 mask = __ballot(cand);
        if (mask) {
            // compact append via mbcnt (lanes below me in mask)
            u32 below = __builtin_amdgcn_mbcnt_hi(
                (u32)(mask >> 32), __builtin_amdgcn_mbcnt_lo((u32)mask, 0));
            if (cand) sbuf[wave][cnt + below] = kk;
            cnt += (int)__popcll(mask);
            if (cnt >= 64) {  // flush a full batch of 64
                u64 c = sbuf[wave][lane];
                c = lane_sort64(c, lane);
                m = lane_merge64(m, c, lane);
                tau = shfl_u64(m, 31);
                int rem = cnt - 64;
                if (lane < rem) sbuf[wave][lane] = sbuf[wave][64 + lane];
                cnt = rem;
            }
        }
    }
    // drain leftovers (<= 127 keys -> at most 2 batches)
    while (cnt > 0) {
        int take = cnt < 64 ? cnt : 64;
        u64 v = sbuf[wave][lane];
        u64 c = (lane < take) ? v : ~0ull;
        c = lane_sort64(c, lane);
        m = lane_merge64(m, c, lane);
        int rem = cnt - take;
        if (lane < rem) sbuf[wave][lane] = sbuf[wave][64 + lane];
        cnt = rem;
    }

    // lanes 0..31 hold the exact global top-32, ascending (== stable top_k)
    if (lane < KNN_K) {
        int n = (int)(u32)m;
        size_t o = (size_t)cid * (KNN_K * 3) + (size_t)lane * 3;
        out[o + 0] = __fsub_rn(xp[n], cx);
        out[o + 1] = __fsub_rn(yp[n], cy);
        out[o + 2] = __fsub_rn(zp[n], cz);
    }
}

extern "C" void kernel_launch(void* const* d_in, const int* in_sizes, int n_in,
                              void* d_out, int out_size, void* d_ws, size_t ws_size,
                              hipStream_t stream) {
    const float* in  = (const float*)d_in[0];
    float* out       = (float*)d_out;
    float* centers   = out + (size_t)BATCH * NGRP * KNN_K * 3;  // second output section

    fps_kernel<<<BATCH, FPS_T, 0, stream>>>(in, centers);
    knn_kernel<<<(BATCH * NGRP) / KNN_WPB, KNN_WPB * 64, 0, stream>>>(in, centers, out);
}

// Round 11
// 586.158 us; speedup vs baseline: 1.2004x; 1.2004x over previous
//
#include <hip/hip_runtime.h>

typedef unsigned long long u64;
typedef unsigned int u32;
typedef float v2f __attribute__((ext_vector_type(2)));

// Problem constants (from reference setup_inputs / NUM_GROUP / GROUP_SIZE)
#define BATCH 32
#define NPTS  8192
#define NGRP  512
#define KNN_K 32

#define FPS_T 256                  // threads per FPS block (4 waves) -- R4 champion config
#define FPS_W (FPS_T / 64)         // 4 waves
#define PPAIR (NPTS / FPS_T / 2)   // 16 point-PAIRS per thread
#define KNN_WPB 4                  // waves (centers) per kNN block
#define QCAP 128                   // per-wave LDS candidate buffer depth

// Exact IEEE (no FMA contraction) squared distance: ((dx*dx + dy*dy) + dz*dz)
__device__ __forceinline__ float sq3(float dx, float dy, float dz) {
    return __fadd_rn(__fadd_rn(__fmul_rn(dx, dx), __fmul_rn(dy, dy)), __fmul_rn(dz, dz));
}

// d >= 0 always (sum of squares) -> IEEE bits are order-monotonic.
// key = (d_bits << 32) | idx  ==> u64 ascending == (d, idx) lexicographic.
__device__ __forceinline__ u64 packdi(float d, int n) {
    return ((u64)__float_as_uint(d) << 32) | (u32)n;
}

__device__ __forceinline__ u64 umin64(u64 a, u64 b) { return a < b ? a : b; }
__device__ __forceinline__ u64 umax64(u64 a, u64 b) { return a > b ? a : b; }

__device__ __forceinline__ u64 shfl_xor_u64(u64 v, int m) {
    int lo = __shfl_xor((int)(u32)v, m, 64);
    int hi = __shfl_xor((int)(u32)(v >> 32), m, 64);
    return ((u64)(u32)hi << 32) | (u32)lo;
}

__device__ __forceinline__ u64 shfl_u64(u64 v, int src) {
    int lo = __shfl((int)(u32)v, src, 64);
    int hi = __shfl((int)(u32)(v >> 32), src, 64);
    return ((u64)(u32)hi << 32) | (u32)lo;
}

// ---- DPP wave-64 u64-max reduction (result valid in lane 63) --------------
// update_dpp(old=0, bound_ctrl=1): lanes with invalid DPP source read 0.
// 0 is a safe identity: every real key has low32 = ~n >= 0xFFFFE000 > 0.
template <int CTRL>
__device__ __forceinline__ u64 dpp_max_step(u64 k) {
    u32 plo = (u32)__builtin_amdgcn_update_dpp(0, (int)(u32)k, CTRL, 0xF, 0xF, true);
    u32 phi = (u32)__builtin_amdgcn_update_dpp(0, (int)(u32)(k >> 32), CTRL, 0xF, 0xF, true);
    u64 p = ((u64)phi << 32) | plo;
    return k > p ? k : p;
}
__device__ __forceinline__ u64 dpp_wave_max(u64 k) {
    k = dpp_max_step<0x111>(k);  // row_shr:1
    k = dpp_max_step<0x112>(k);  // row_shr:2
    k = dpp_max_step<0x114>(k);  // row_shr:4
    k = dpp_max_step<0x118>(k);  // row_shr:8   -> lanes 15/31/47/63 = row max
    k = dpp_max_step<0x142>(k);  // row_bcast15 -> lane31 = rows0-1, lane63 = rows2-3
    k = dpp_max_step<0x143>(k);  // row_bcast31 -> lane63 = full wave
    return k;
}

// Cross-lane bitonic sort: one u64 per lane -> ascending by lane index.
__device__ __forceinline__ u64 lane_sort64(u64 v, int lane) {
#pragma unroll
    for (int k = 2; k <= 64; k <<= 1) {
#pragma unroll
        for (int j = k >> 1; j > 0; j >>= 1) {
            u64 p = shfl_xor_u64(v, j);
            bool keepmin = (((lane & k) == 0) == ((lane & j) == 0));
            u64 mn = umin64(v, p), mx = umax64(v, p);
            v = keepmin ? mn : mx;
        }
    }
    return v;
}

// m, c both ascending-sorted across lanes; returns the lowest 64 of the 128,
// ascending-sorted. (reverse c, elementwise min -> bitonic, 6-level clean)
__device__ __forceinline__ u64 lane_merge64(u64 m, u64 c, int lane) {
    u64 cr = shfl_xor_u64(c, 63);
    u64 z = umin64(m, cr);
#pragma unroll
    for (int dd = 32; dd > 0; dd >>= 1) {
        u64 p = shfl_xor_u64(z, dd);
        u64 mn = umin64(z, p), mx = umax64(z, p);
        z = (lane & dd) ? mx : mn;
    }
    return z;
}

// ---------------------------------------------------------------------------
// FPS (R4 champion structure, 434 us measured): one block per batch, 256
// threads, 32 points/thread as 16 float2 pairs. Round loop: per-pair packed
// distance (contract(off): per-op IEEE rounding == numpy) + fmin update +
// in-loop strict-> (bd,bi) tracking per half (tie -> lowest n since n is
// ascending). u64 (d_bits, ~n) pack once per round, 6-step DPP wave argmax
// (lane 63), single barrier, double-buffered 4-partial exchange, scalar b32
// coord broadcasts. Centers buffered in LDS, written coalesced at the end.
// ---------------------------------------------------------------------------
__global__ __launch_bounds__(FPS_T) void fps_kernel(const float* __restrict__ in,
                                                    float* __restrict__ centers) {
#pragma clang fp contract(off)
    __shared__ float sx[NPTS];           // 32 KB
    __shared__ float sy[NPTS];           // 32 KB
    __shared__ float sz[NPTS];           // 32 KB
    __shared__ u64 s_key[2][FPS_W];      // double-buffered wave partials
    __shared__ float s_out[NGRP * 3];    // 6 KB center-coord buffer

    const int b = blockIdx.x;
    const int t = threadIdx.x;
    const int w = t >> 6;
    const float* xp = in + (size_t)b * 3 * NPTS;
    const float* yp = xp + NPTS;
    const float* zp = xp + 2 * NPTS;

    v2f xr[PPAIR], yr[PPAIR], zr[PPAIR], md[PPAIR];
#pragma unroll
    for (int i = 0; i < PPAIR; ++i) {
        int n = i * (2 * FPS_T) + 2 * t;       // pair covers points n, n+1
        xr[i] = *(const v2f*)(xp + n);
        yr[i] = *(const v2f*)(yp + n);
        zr[i] = *(const v2f*)(zp + n);
        *(v2f*)(sx + n) = xr[i];
        *(v2f*)(sy + n) = yr[i];
        *(v2f*)(sz + n) = zr[i];
        md[i] = (v2f){1e10f, 1e10f};
    }
    __syncthreads();

    int cur = 0;
    for (int r = 0; r < NGRP; ++r) {
        const float cx = sx[cur], cy = sy[cur], cz = sz[cur];  // b32 broadcasts
        if (t == 0) {  // idxs[r] is the PRE-update farthest -> buffer coords
            s_out[r * 3 + 0] = cx;
            s_out[r * 3 + 1] = cy;
            s_out[r * 3 + 2] = cz;
        }

        float bd0 = -1.0f, bd1 = -1.0f;
        int   bi0 = 0,     bi1 = 0;
#pragma unroll
        for (int i = 0; i < PPAIR; ++i) {
            v2f dx = xr[i] - cx;
            v2f dy = yr[i] - cy;
            v2f dz = zr[i] - cz;
            v2f dd = dx * dx + dy * dy + dz * dz;  // contract(off): 3 mul + 2 add
            md[i] = __builtin_elementwise_min(md[i], dd);
            int n = i * (2 * FPS_T) + 2 * t;
            if (md[i].x > bd0) { bd0 = md[i].x; bi0 = n; }      // strict >: first max
            if (md[i].y > bd1) { bd1 = md[i].y; bi1 = n + 1; }
        }
        // max (d, tie -> lowest n) == u64 max of (d_bits, ~n)
        u64 k0 = ((u64)__float_as_uint(bd0) << 32) | (u32)(~(u32)bi0);
        u64 k1 = ((u64)__float_as_uint(bd1) << 32) | (u32)(~(u32)bi1);
        u64 k = dpp_wave_max(umax64(k0, k1));
        if ((t & 63) == 63) s_key[r & 1][w] = k;  // lane 63 holds wave winner
        __syncthreads();
        u64 m = umax64(umax64(s_key[r & 1][0], s_key[r & 1][1]),
                       umax64(s_key[r & 1][2], s_key[r & 1][3]));
        cur = (int)(~(u32)m);  // recover winning index
    }

    __syncthreads();  // t0's last s_out writes
    float* cdst = centers + (size_t)b * NGRP * 3;
    for (int i = t; i < NGRP * 3; i += FPS_T) cdst[i] = s_out[i];
}

// ---------------------------------------------------------------------------
// kNN + gather: one wave per center. Wave-cooperative exact top-32 with a
// DEFERRED LDS candidate buffer: m = sorted-64 register list (lanes 0..31 =
// exact running top-32 of all merged keys), tau = m[31] (exact 32nd).
// Candidates (kk < tau) are compacted into a 128-deep per-wave LDS buffer
// via ballot+mbcnt (no atomics); sort64+merge fires only when >=64 have
// accumulated. Strict < filter + unique keys => exactness; drain loop
// merges leftovers. (R6-R10: ~165 us, unchanged.)
// ---------------------------------------------------------------------------
__global__ __launch_bounds__(KNN_WPB * 64) void knn_kernel(const float* __restrict__ in,
                                                           const float* __restrict__ centers,
                                                           float* __restrict__ out) {
    __shared__ u64 sbuf[KNN_WPB][QCAP];  // 4 KB candidate buffers

    const int wave = threadIdx.x >> 6;
    const int lane = threadIdx.x & 63;
    const int cid  = blockIdx.x * KNN_WPB + wave;   // [0, B*G)
    const int b    = cid >> 9;                      // /NGRP

    const float* xp = in + (size_t)b * 3 * NPTS;
    const float* yp = xp + NPTS;
    const float* zp = xp + 2 * NPTS;

    const float cx = centers[cid * 3 + 0];
    const float cy = centers[cid * 3 + 1];
    const float cz = centers[cid * 3 + 2];

    // seed: column 0 (points 0..63), exact sorted top-64
    float x = xp[lane], y = yp[lane], z = zp[lane];
    u64 m = packdi(sq3(__fsub_rn(x, cx), __fsub_rn(y, cy), __fsub_rn(z, cz)), lane);
    m = lane_sort64(m, lane);
    u64 tau = shfl_u64(m, 31);
    int cnt = 0;  // wave-uniform buffered-candidate count

    float nx = xp[64 + lane], ny = yp[64 + lane], nz = zp[64 + lane];
#pragma unroll 1
    for (int j = 1; j < NPTS / 64; ++j) {
        x = nx; y = ny; z = nz;
        if (j + 1 < NPTS / 64) {  // 1-deep prefetch
            int n2 = (j + 1) * 64 + lane;
            nx = xp[n2]; ny = yp[n2]; nz = zp[n2];
        }
        float d = sq3(__fsub_rn(x, cx), __fsub_rn(y, cy), __fsub_rn(z, cz));
        u64 kk = packdi(d, j * 64 + lane);
        bool cand = kk < tau;  // strict: excluded keys provably > global 32nd
        u64 mask = __ballot(cand);
        if (mask) {
            // compact append via mbcnt (lanes below me in mask)
            u32 below = __builtin_amdgcn_mbcnt_hi(
                (u32)(mask >> 32), __builtin_amdgcn_mbcnt_lo((u32)mask, 0));
            if (cand) sbuf[wave][cnt + below] = kk;
            cnt += (int)__popcll(mask);
            if (cnt >= 64) {  // flush a full batch of 64
                u64 c = sbuf[wave][lane];
                c = lane_sort64(c, lane);
                m = lane_merge64(m, c, lane);
                tau = shfl_u64(m, 31);
                int rem = cnt - 64;
                if (lane < rem) sbuf[wave][lane] = sbuf[wave][64 + lane];
                cnt = rem;
            }
        }
    }
    // drain leftovers (<= 127 keys -> at most 2 batches)
    while (cnt > 0) {
        int take = cnt < 64 ? cnt : 64;
        u64 v = sbuf[wave][lane];
        u64 c = (lane < take) ? v : ~0ull;
        c = lane_sort64(c, lane);
        m = lane_merge64(m, c, lane);
        int rem = cnt - take;
        if (lane < rem) sbuf[wave][lane] = sbuf[wave][64 + lane];
        cnt = rem;
    }

    // lanes 0..31 hold the exact global top-32, ascending (== stable top_k)
    if (lane < KNN_K) {
        int n = (int)(u32)m;
        size_t o = (size_t)cid * (KNN_K * 3) + (size_t)lane * 3;
        out[o + 0] = __fsub_rn(xp[n], cx);
        out[o + 1] = __fsub_rn(yp[n], cy);
        out[o + 2] = __fsub_rn(zp[n], cz);
    }
}

extern "C" void kernel_launch(void* const* d_in, const int* in_sizes, int n_in,
                              void* d_out, int out_size, void* d_ws, size_t ws_size,
                              hipStream_t stream) {
    const float* in  = (const float*)d_in[0];
    float* out       = (float*)d_out;
    float* centers   = out + (size_t)BATCH * NGRP * KNN_K * 3;  // second output section

    fps_kernel<<<BATCH, FPS_T, 0, stream>>>(in, centers);
    knn_kernel<<<(BATCH * NGRP) / KNN_WPB, KNN_WPB * 64, 0, stream>>>(in, centers, out);
}